// Round 8
// baseline (375.250 us; speedup 1.0000x reference)
//
#include <hip/hip_runtime.h>
#include <hip/hip_bf16.h>
#include <cstdint>
#include <cstddef>

// ---------------- constants ----------------
#define T_SEQ   2048
#define BATCH   2
#define DMODEL  2048
#define NHEAD   16
#define DHEAD   128
#define CH      144          // NHEAD + DHEAD
#define RQ      6
#define RKV     4            // R_K + R_V
#define N1      1440         // (RQ+RKV)*CH
#define N1P     1536         // padded to multiple of 128
#define MROWS   4096         // B*T

typedef short bf16x8 __attribute__((ext_vector_type(8)));
typedef float f32x4  __attribute__((ext_vector_type(4)));

#if defined(__has_builtin)
#  if __has_builtin(__builtin_amdgcn_exp2f)
#    define EXP2(x) __builtin_amdgcn_exp2f(x)
#  else
#    define EXP2(x) exp2f(x)
#  endif
#else
#  define EXP2(x) exp2f(x)
#endif

__device__ __forceinline__ float bflo(unsigned u){ return __uint_as_float(u << 16); }
__device__ __forceinline__ float bfhi(unsigned u){ return __uint_as_float(u & 0xffff0000u); }
__device__ __forceinline__ unsigned short f2bf(float f){
  unsigned b = __float_as_uint(f);
  b += 0x7fffu + ((b >> 16) & 1u);
  return (unsigned short)(b >> 16);
}

// ---------------- cast fp32 -> bf16 (vectorized) ----------------
__global__ void cast_f32_bf16(const float* __restrict__ src, unsigned short* __restrict__ dst, int n4){
  int i = blockIdx.x * blockDim.x + threadIdx.x;
  int stride = gridDim.x * blockDim.x;
  for (; i < n4; i += stride){
    float4 v = ((const float4*)src)[i];
    ushort4 o;
    o.x = f2bf(v.x); o.y = f2bf(v.y); o.z = f2bf(v.z); o.w = f2bf(v.w);
    ((ushort4*)dst)[i] = o;
  }
}

__global__ void zero_u16(unsigned short* __restrict__ dst, int n){
  int i = blockIdx.x * blockDim.x + threadIdx.x;
  if (i < n) dst[i] = 0;
}

// ---------------- bf16 GEMM: C(MxN,f32) = A(MxK) * B(NxK)^T ----------------
#define GBK 32
__global__ __launch_bounds__(256) void gemm_bt(const unsigned short* __restrict__ A,
                                               const unsigned short* __restrict__ Bm,
                                               float* __restrict__ C,
                                               int M, int N, int K){
  __shared__ __align__(16) unsigned short As[128 * GBK];
  __shared__ __align__(16) unsigned short Bs[128 * GBK];
  const int tid  = threadIdx.x;
  const int lane = tid & 63;
  const int wv   = tid >> 6;
  const int m0   = blockIdx.y * 128;
  const int n0   = blockIdx.x * 128;
  const int wm   = wv >> 1, wn = wv & 1;

  f32x4 acc[4][4];
#pragma unroll
  for (int i = 0; i < 4; ++i)
#pragma unroll
    for (int j = 0; j < 4; ++j) acc[i][j] = (f32x4){0.f, 0.f, 0.f, 0.f};

  const int srow = lane >> 2;
  const int scol = (lane & 3) * 8;
  const int kq   = (lane >> 4) * 8;
  const int rA   = lane & 15;

  for (int kt = 0; kt < K; kt += GBK){
#pragma unroll
    for (int i = 0; i < 2; ++i){
      int j = wv * 2 + i;
      int r = j * 16 + srow;
      const unsigned short* ga = A  + (size_t)(m0 + r) * K + kt + scol;
      const unsigned short* gb = Bm + (size_t)(n0 + r) * K + kt + scol;
      __builtin_amdgcn_global_load_lds((const __attribute__((address_space(1))) void*)ga,
                                       (__attribute__((address_space(3))) void*)&As[j * 16 * GBK], 16, 0, 0);
      __builtin_amdgcn_global_load_lds((const __attribute__((address_space(1))) void*)gb,
                                       (__attribute__((address_space(3))) void*)&Bs[j * 16 * GBK], 16, 0, 0);
    }
    __syncthreads();

    bf16x8 af[4], bfv[4];
#pragma unroll
    for (int mi = 0; mi < 4; ++mi)
      af[mi] = *(const bf16x8*)&As[(wm * 64 + mi * 16 + rA) * GBK + kq];
#pragma unroll
    for (int ni = 0; ni < 4; ++ni)
      bfv[ni] = *(const bf16x8*)&Bs[(wn * 64 + ni * 16 + rA) * GBK + kq];
#pragma unroll
    for (int mi = 0; mi < 4; ++mi)
#pragma unroll
      for (int ni = 0; ni < 4; ++ni)
        acc[mi][ni] = __builtin_amdgcn_mfma_f32_16x16x32_bf16(af[mi], bfv[ni], acc[mi][ni], 0, 0, 0);
    __syncthreads();
  }

#pragma unroll
  for (int mi = 0; mi < 4; ++mi)
#pragma unroll
    for (int ni = 0; ni < 4; ++ni){
      int row = m0 + wm * 64 + mi * 16 + (lane >> 4) * 4;
      int col = n0 + wn * 64 + ni * 16 + (lane & 15);
#pragma unroll
      for (int r = 0; r < 4; ++r)
        C[(size_t)(row + r) * N + col] = acc[mi][ni][r];
    }
}

// ---------------- qkv: tensor-product contraction + RoPE ----------------
// q output is pre-scaled by SCL = (1/sqrt(128))*log2(e) so attention's QK^T lands
// directly in the exp2 domain (v4: fold removes attn's per-phase Q repack).
#define QSCL 0.021254252143473517f   // SCL / 6
__global__ __launch_bounds__(256) void qkv_kernel(const float* __restrict__ ab,
                                                  unsigned short* __restrict__ qb,
                                                  unsigned short* __restrict__ kb,
                                                  unsigned short* __restrict__ vb){
  __shared__ float sab[N1];
  const int bt = blockIdx.x;
  const int b  = bt >> 11;
  const int t  = bt & 2047;
  const float* row = ab + (size_t)bt * N1P;
  for (int j = threadIdx.x; j < N1; j += 256) sab[j] = row[j];
  __syncthreads();

  {
    int r = threadIdx.x >> 6;
    int d = threadIdx.x & 63;
    float inv = exp2f(-(float)d * 0.20762050593046f);
    float fr  = (float)t * inv;
    float c = cosf(fr), s = sinf(fr);
    float x1 = sab[864 + r * CH + 16 + d];
    float x2 = sab[864 + r * CH + 16 + 64 + d];
    sab[864 + r * CH + 16 + d]      = x1 * c + x2 * s;
    sab[864 + r * CH + 16 + 64 + d] = x2 * c - x1 * s;
  }
  __syncthreads();

  const int h  = threadIdx.x >> 4;
  const int d0 = (threadIdx.x & 15) * 8;

  {
    float aq[RQ];
#pragma unroll
    for (int r = 0; r < RQ; ++r) aq[r] = sab[r * CH + h];
    union { unsigned short u16[8]; uint4 v; } pk;
#pragma unroll
    for (int j = 0; j < 8; ++j){
      float acc = 0.f;
#pragma unroll
      for (int r = 0; r < RQ; ++r) acc += aq[r] * sab[r * CH + 16 + d0 + j];
      pk.u16[j] = f2bf(acc * QSCL);
    }
    *(uint4*)&qb[((size_t)(b * 16 + h) * T_SEQ + t) * DHEAD + d0] = pk.v;
  }
  {
    float a0 = sab[864 + 0 * CH + h], a1 = sab[864 + 1 * CH + h];
    union { unsigned short u16[8]; uint4 v; } pk;
#pragma unroll
    for (int j = 0; j < 8; ++j){
      float acc = a0 * sab[864 + 0 * CH + 16 + d0 + j] + a1 * sab[864 + 1 * CH + 16 + d0 + j];
      pk.u16[j] = f2bf(acc * 0.5f);
    }
    *(uint4*)&kb[((size_t)(b * 16 + h) * T_SEQ + t) * DHEAD + d0] = pk.v;
  }
  {
    float a0 = sab[864 + 2 * CH + h], a1 = sab[864 + 3 * CH + h];
    union { unsigned short u16[8]; uint4 v; } pk;
#pragma unroll
    for (int j = 0; j < 8; ++j){
      float acc = a0 * sab[864 + 2 * CH + 16 + d0 + j] + a1 * sab[864 + 3 * CH + 16 + d0 + j];
      pk.u16[j] = f2bf(acc * 0.5f);
    }
    *(uint4*)&vb[((size_t)(b * 16 + h) * T_SEQ + t) * DHEAD + d0] = pk.v;
  }
}

// ---------------- MFMA causal flash attention (v4: fused pair, 16 waves) ----------------
// 256 blocks x 1024 threads: block = (bh, pr). Waves 0-7 compute q-tile (15-pr),
// waves 8-15 q-tile pr, SHARING one kv stream (light tile's kv range is a prefix;
// the per-wave guard idles light waves on late tiles). 16 waves/CU = 4/SIMD.
// K via global_load_lds w/ inverse-swizzled source; V reg-transposed split-staged (T14);
// Q arrives pre-scaled from qkv; exp2-domain softmax; defer-max (T13); setprio (T5).
__global__ __launch_bounds__(1024) void attn_mfma(const unsigned short* __restrict__ qg,
                                                  const unsigned short* __restrict__ kg,
                                                  const unsigned short* __restrict__ vg,
                                                  unsigned short* __restrict__ yg){
  __shared__ __align__(16) unsigned short Ks[2 * 64 * DHEAD];   // 32 KB
  __shared__ __align__(16) unsigned short Vt[2 * DHEAD * 64];   // 32 KB
  __shared__ __align__(16) unsigned short Ps[16 * 16 * 64];     // 32 KB

  const int bi   = blockIdx.x;
  const int xcd  = bi & 7;
  const int slot = bi >> 3;               // 0..31
  const int bh   = (slot & 3) * 8 + xcd;  // 0..31
  const int pr   = slot >> 2;             // 0..7
  const int b    = bh >> 4;
  const int h    = bh & 15;
  const size_t base = (size_t)bh * T_SEQ * DHEAD;

  const int lane = threadIdx.x & 63;
  const int wv   = threadIdx.x >> 6;      // 0..15
  const int wl   = wv & 7;
  const int lo   = lane & 15;
  const int hi   = lane >> 4;

  const int qt    = (wv < 8) ? (15 - pr) : pr;
  const int qrow0 = qt * 128 + wl * 16;   // 16 rows per wave
  const int nt    = 2 * (15 - pr) + 2;    // kv tiles for the heavy tile (block-uniform)

  // Q fragments (already scaled in qkv)
  bf16x8 qf[4];
#pragma unroll
  for (int ds = 0; ds < 4; ++ds)
    qf[ds] = *(const bf16x8*)(qg + base + (size_t)(qrow0 + lo) * DHEAD + ds * 32 + hi * 8);

  f32x4 o4[8];
#pragma unroll
  for (int dcb = 0; dcb < 8; ++dcb) o4[dcb] = (f32x4){0.f,0.f,0.f,0.f};
  float mrow[4], lrow[4];
#pragma unroll
  for (int r = 0; r < 4; ++r){ mrow[r] = -1e30f; lrow[r] = 0.f; }

  // prologue: stage tile 0 into buffer 0 (1024 threads: 1 K-chunk + 1 V-chunk each)
  {
    int c    = threadIdx.x;                 // chunk id 0..1023
    int row  = c >> 4;
    int gcol = (c & 15) ^ (row & 7);
    const unsigned short* src = kg + base + (size_t)row * DHEAD + gcol * 8;
    __builtin_amdgcn_global_load_lds((const __attribute__((address_space(1))) void*)src,
                                     (__attribute__((address_space(3))) void*)&Ks[wv * 512], 16, 0, 0);
    uint4 tv = *(const uint4*)(vg + base + (size_t)lane * DHEAD + wv * 8);
    union { uint4 v; unsigned short u[8]; } t2; t2.v = tv;
#pragma unroll
    for (int j = 0; j < 8; ++j)
      Vt[(wv * 8 + j) * 64 + (lane ^ (j << 3))] = t2.u[j];
    __syncthreads();
  }

  for (int kt = 0; kt < nt; ++kt){
    const int cur = kt & 1;
    const int nxt = cur ^ 1;
    const bool pf = (kt + 1 < nt);
    uint4 tv;
    if (pf){
      // prefetch K(kt+1) straight to LDS buffer nxt
      int c    = threadIdx.x;
      int row  = c >> 4;
      int gcol = (c & 15) ^ (row & 7);
      const unsigned short* src = kg + base + (size_t)((kt + 1) * 64 + row) * DHEAD + gcol * 8;
      __builtin_amdgcn_global_load_lds((const __attribute__((address_space(1))) void*)src,
                                       (__attribute__((address_space(3))) void*)&Ks[nxt * 8192 + wv * 512], 16, 0, 0);
      // prefetch V(kt+1) to registers
      tv = *(const uint4*)(vg + base + (size_t)((kt + 1) * 64 + lane) * DHEAD + wv * 8);
    }

    if (kt * 64 <= qrow0 + 15){   // wave has unmasked work in this tile
      const unsigned short* Kb = &Ks[cur * 8192];
      const unsigned short* Vb = &Vt[cur * 8192];

      // ---- S = Q K^T (scores in exp2 domain) ----
      f32x4 s4[4];
#pragma unroll
      for (int cb = 0; cb < 4; ++cb) s4[cb] = (f32x4){0.f,0.f,0.f,0.f};
      __builtin_amdgcn_s_setprio(1);
#pragma unroll
      for (int ds = 0; ds < 4; ++ds){
        bf16x8 kf[4];
#pragma unroll
        for (int cb = 0; cb < 4; ++cb){
          int kvr = cb * 16 + lo;
          kf[cb] = *(const bf16x8*)&Kb[kvr * DHEAD + ((ds * 32 + hi * 8) ^ ((kvr & 7) << 3))];
        }
#pragma unroll
        for (int cb = 0; cb < 4; ++cb)
          s4[cb] = __builtin_amdgcn_mfma_f32_16x16x32_bf16(qf[ds], kf[cb], s4[cb], 0, 0, 0);
      }
      __builtin_amdgcn_s_setprio(0);

      // ---- causal mask (diagonal tiles only) ----
      if (kt * 64 + 63 > qrow0){
#pragma unroll
        for (int cb = 0; cb < 4; ++cb)
#pragma unroll
          for (int r = 0; r < 4; ++r){
            int kv = kt * 64 + cb * 16 + lo;
            int q  = qrow0 + hi * 4 + r;
            if (kv > q) s4[cb][r] = -1e30f;
          }
      }

      // ---- online softmax (exp2 domain), defer-max ----
      float mx8[4];
#pragma unroll
      for (int r = 0; r < 4; ++r){
        float mx = fmaxf(fmaxf(s4[0][r], s4[1][r]), fmaxf(s4[2][r], s4[3][r]));
        mx = fmaxf(mx, __shfl_xor(mx, 1));
        mx = fmaxf(mx, __shfl_xor(mx, 2));
        mx = fmaxf(mx, __shfl_xor(mx, 4));
        mx = fmaxf(mx, __shfl_xor(mx, 8));
        mx8[r] = mx;
      }
      bool grow = false;
#pragma unroll
      for (int r = 0; r < 4; ++r) grow |= (mx8[r] > mrow[r] + 8.f);
      if (__any(grow)){
#pragma unroll
        for (int r = 0; r < 4; ++r){
          float mN = fmaxf(mrow[r], mx8[r]);
          float alpha = EXP2(mrow[r] - mN);
          mrow[r] = mN;
          lrow[r] *= alpha;
#pragma unroll
          for (int dcb = 0; dcb < 8; ++dcb) o4[dcb][r] *= alpha;
        }
      }
#pragma unroll
      for (int r = 0; r < 4; ++r){
        float m = mrow[r];
        float p0 = EXP2(s4[0][r] - m);
        float p1 = EXP2(s4[1][r] - m);
        float p2 = EXP2(s4[2][r] - m);
        float p3 = EXP2(s4[3][r] - m);
        float ps = p0 + p1 + p2 + p3;
        ps += __shfl_xor(ps, 1);
        ps += __shfl_xor(ps, 2);
        ps += __shfl_xor(ps, 4);
        ps += __shfl_xor(ps, 8);
        lrow[r] += ps;
        int qloc = hi * 4 + r;                       // 0..15
        int sw   = ((qloc + (qloc >> 3)) & 7) << 3;
        int pb   = wv * 1024 + qloc * 64;
        Ps[pb + ((0 * 16 + lo) ^ sw)] = f2bf(p0);
        Ps[pb + ((1 * 16 + lo) ^ sw)] = f2bf(p1);
        Ps[pb + ((2 * 16 + lo) ^ sw)] = f2bf(p2);
        Ps[pb + ((3 * 16 + lo) ^ sw)] = f2bf(p3);
      }

      // wave-local P round-trip: ensure ds_writes retired before ds_reads
      asm volatile("s_waitcnt lgkmcnt(0)" ::: "memory");

      // ---- O += P V ----
      __builtin_amdgcn_s_setprio(1);
#pragma unroll
      for (int ks = 0; ks < 2; ++ks){
        bf16x8 pa;
        {
          int qloc = lo;                             // 0..15
          int sw   = ((qloc + (qloc >> 3)) & 7) << 3;
          pa = *(const bf16x8*)&Ps[wv * 1024 + qloc * 64 + ((ks * 32 + hi * 8) ^ sw)];
        }
#pragma unroll
        for (int dcb = 0; dcb < 8; ++dcb){
          int d = dcb * 16 + lo;
          bf16x8 vf = *(const bf16x8*)&Vb[d * 64 + ((ks * 32 + hi * 8) ^ ((d & 7) << 3))];
          o4[dcb] = __builtin_amdgcn_mfma_f32_16x16x32_bf16(pa, vf, o4[dcb], 0, 0, 0);
        }
      }
      __builtin_amdgcn_s_setprio(0);
    }

    if (pf){
      // write prefetched V into buffer nxt (compiler waits vmcnt for tv here)
      union { uint4 v; unsigned short u[8]; } t2; t2.v = tv;
#pragma unroll
      for (int j = 0; j < 8; ++j)
        Vt[nxt * 8192 + (wv * 8 + j) * 64 + (lane ^ (j << 3))] = t2.u[j];
    }
    __syncthreads();   // drains K global_load_lds for kt+1; fences buffers
  }

  // ---- epilogue: normalize + store bf16 y[b, t, h*128 + d] ----
#pragma unroll
  for (int r = 0; r < 4; ++r){
    float inv = 1.f / lrow[r];
    int q = qrow0 + hi * 4 + r;
    size_t yb_ = ((size_t)(b * T_SEQ + q)) * DMODEL + h * DHEAD;
#pragma unroll
    for (int dcb = 0; dcb < 8; ++dcb)
      yg[yb_ + dcb * 16 + lo] = f2bf(o4[dcb][r] * inv);
  }
}

// ---------------- launch ----------------
extern "C" void kernel_launch(void* const* d_in, const int* in_sizes, int n_in,
                              void* d_out, int out_size, void* d_ws, size_t ws_size,
                              hipStream_t stream) {
  const float* x   = (const float*)d_in[0];
  const float* Wq  = (const float*)d_in[1];
  const float* Wkv = (const float*)d_in[2];
  const float* Wo  = (const float*)d_in[3];
  float* out = (float*)d_out;

  char* ws = (char*)d_ws;
  size_t off = 0;
  auto alloc = [&](size_t bytes) -> void* {
    void* p = ws + off;
    off += (bytes + 255) & ~(size_t)255;
    return p;
  };
  unsigned short* xb = (unsigned short*)alloc((size_t)MROWS * DMODEL * 2);
  unsigned short* wc = (unsigned short*)alloc((size_t)N1P * DMODEL * 2);
  unsigned short* wo = (unsigned short*)alloc((size_t)DMODEL * DMODEL * 2);
  float*          abf = (float*)alloc((size_t)MROWS * N1P * 4);
  unsigned short* qb = (unsigned short*)alloc((size_t)MROWS * DMODEL * 2);
  unsigned short* kb = (unsigned short*)alloc((size_t)MROWS * DMODEL * 2);
  unsigned short* vb = (unsigned short*)alloc((size_t)MROWS * DMODEL * 2);
  unsigned short* yb = (unsigned short*)alloc((size_t)MROWS * DMODEL * 2);

  {
    int n4 = MROWS * DMODEL / 4;
    cast_f32_bf16<<<2048, 256, 0, stream>>>(x, xb, n4);
    n4 = RQ * CH * DMODEL / 4;
    cast_f32_bf16<<<1024, 256, 0, stream>>>(Wq, wc, n4);
    n4 = RKV * CH * DMODEL / 4;
    cast_f32_bf16<<<1024, 256, 0, stream>>>(Wkv, wc + (size_t)RQ * CH * DMODEL, n4);
    int npad = (N1P - N1) * DMODEL;
    zero_u16<<<(npad + 255) / 256, 256, 0, stream>>>(wc + (size_t)N1 * DMODEL, npad);
    n4 = DMODEL * DMODEL / 4;
    cast_f32_bf16<<<2048, 256, 0, stream>>>(Wo, wo, n4);
  }

  gemm_bt<<<dim3(N1P / 128, MROWS / 128), 256, 0, stream>>>(xb, wc, abf, MROWS, N1P, DMODEL);
  qkv_kernel<<<MROWS, 256, 0, stream>>>(abf, qb, kb, vb);
  attn_mfma<<<256, 1024, 0, stream>>>(qb, kb, vb, yb);
  gemm_bt<<<dim3(DMODEL / 128, MROWS / 128), 256, 0, stream>>>(yb, wo, out, MROWS, DMODEL, DMODEL);
}

// Round 9
// 322.308 us; speedup vs baseline: 1.1643x; 1.1643x over previous
//
#include <hip/hip_runtime.h>
#include <hip/hip_bf16.h>
#include <cstdint>
#include <cstddef>

// ---------------- constants ----------------
#define T_SEQ   2048
#define BATCH   2
#define DMODEL  2048
#define NHEAD   16
#define DHEAD   128
#define CH      144          // NHEAD + DHEAD
#define RQ      6
#define RKV     4            // R_K + R_V
#define N1      1440         // (RQ+RKV)*CH
#define N1P     1536         // padded to multiple of 128
#define MROWS   4096         // B*T

typedef short bf16x8 __attribute__((ext_vector_type(8)));
typedef float f32x4  __attribute__((ext_vector_type(4)));

#if defined(__has_builtin)
#  if __has_builtin(__builtin_amdgcn_exp2f)
#    define EXP2(x) __builtin_amdgcn_exp2f(x)
#  else
#    define EXP2(x) exp2f(x)
#  endif
#else
#  define EXP2(x) exp2f(x)
#endif

__device__ __forceinline__ float bflo(unsigned u){ return __uint_as_float(u << 16); }
__device__ __forceinline__ float bfhi(unsigned u){ return __uint_as_float(u & 0xffff0000u); }
__device__ __forceinline__ unsigned short f2bf(float f){
  unsigned b = __float_as_uint(f);
  b += 0x7fffu + ((b >> 16) & 1u);
  return (unsigned short)(b >> 16);
}

// ---------------- cast fp32 -> bf16 (vectorized) ----------------
__global__ void cast_f32_bf16(const float* __restrict__ src, unsigned short* __restrict__ dst, int n4){
  int i = blockIdx.x * blockDim.x + threadIdx.x;
  int stride = gridDim.x * blockDim.x;
  for (; i < n4; i += stride){
    float4 v = ((const float4*)src)[i];
    ushort4 o;
    o.x = f2bf(v.x); o.y = f2bf(v.y); o.z = f2bf(v.z); o.w = f2bf(v.w);
    ((ushort4*)dst)[i] = o;
  }
}

__global__ void zero_u16(unsigned short* __restrict__ dst, int n){
  int i = blockIdx.x * blockDim.x + threadIdx.x;
  if (i < n) dst[i] = 0;
}

// ---------------- bf16 GEMM: C(MxN,f32) = A(MxK) * B(NxK)^T ----------------
#define GBK 32
__global__ __launch_bounds__(256) void gemm_bt(const unsigned short* __restrict__ A,
                                               const unsigned short* __restrict__ Bm,
                                               float* __restrict__ C,
                                               int M, int N, int K){
  __shared__ __align__(16) unsigned short As[128 * GBK];
  __shared__ __align__(16) unsigned short Bs[128 * GBK];
  const int tid  = threadIdx.x;
  const int lane = tid & 63;
  const int wv   = tid >> 6;
  const int m0   = blockIdx.y * 128;
  const int n0   = blockIdx.x * 128;
  const int wm   = wv >> 1, wn = wv & 1;

  f32x4 acc[4][4];
#pragma unroll
  for (int i = 0; i < 4; ++i)
#pragma unroll
    for (int j = 0; j < 4; ++j) acc[i][j] = (f32x4){0.f, 0.f, 0.f, 0.f};

  const int srow = lane >> 2;
  const int scol = (lane & 3) * 8;
  const int kq   = (lane >> 4) * 8;
  const int rA   = lane & 15;

  for (int kt = 0; kt < K; kt += GBK){
#pragma unroll
    for (int i = 0; i < 2; ++i){
      int j = wv * 2 + i;
      int r = j * 16 + srow;
      const unsigned short* ga = A  + (size_t)(m0 + r) * K + kt + scol;
      const unsigned short* gb = Bm + (size_t)(n0 + r) * K + kt + scol;
      __builtin_amdgcn_global_load_lds((const __attribute__((address_space(1))) void*)ga,
                                       (__attribute__((address_space(3))) void*)&As[j * 16 * GBK], 16, 0, 0);
      __builtin_amdgcn_global_load_lds((const __attribute__((address_space(1))) void*)gb,
                                       (__attribute__((address_space(3))) void*)&Bs[j * 16 * GBK], 16, 0, 0);
    }
    __syncthreads();

    bf16x8 af[4], bfv[4];
#pragma unroll
    for (int mi = 0; mi < 4; ++mi)
      af[mi] = *(const bf16x8*)&As[(wm * 64 + mi * 16 + rA) * GBK + kq];
#pragma unroll
    for (int ni = 0; ni < 4; ++ni)
      bfv[ni] = *(const bf16x8*)&Bs[(wn * 64 + ni * 16 + rA) * GBK + kq];
#pragma unroll
    for (int mi = 0; mi < 4; ++mi)
#pragma unroll
      for (int ni = 0; ni < 4; ++ni)
        acc[mi][ni] = __builtin_amdgcn_mfma_f32_16x16x32_bf16(af[mi], bfv[ni], acc[mi][ni], 0, 0, 0);
    __syncthreads();
  }

#pragma unroll
  for (int mi = 0; mi < 4; ++mi)
#pragma unroll
    for (int ni = 0; ni < 4; ++ni){
      int row = m0 + wm * 64 + mi * 16 + (lane >> 4) * 4;
      int col = n0 + wn * 64 + ni * 16 + (lane & 15);
#pragma unroll
      for (int r = 0; r < 4; ++r)
        C[(size_t)(row + r) * N + col] = acc[mi][ni][r];
    }
}

// ---------------- qkv: tensor-product contraction + RoPE ----------------
// q output is pre-scaled by SCL = (1/sqrt(128))*log2(e) so QK^T lands in exp2 domain.
#define QSCL 0.021254252143473517f   // SCL / 6
__global__ __launch_bounds__(256) void qkv_kernel(const float* __restrict__ ab,
                                                  unsigned short* __restrict__ qb,
                                                  unsigned short* __restrict__ kb,
                                                  unsigned short* __restrict__ vb){
  __shared__ float sab[N1];
  const int bt = blockIdx.x;
  const int b  = bt >> 11;
  const int t  = bt & 2047;
  const float* row = ab + (size_t)bt * N1P;
  for (int j = threadIdx.x; j < N1; j += 256) sab[j] = row[j];
  __syncthreads();

  {
    int r = threadIdx.x >> 6;
    int d = threadIdx.x & 63;
    float inv = exp2f(-(float)d * 0.20762050593046f);
    float fr  = (float)t * inv;
    float c = cosf(fr), s = sinf(fr);
    float x1 = sab[864 + r * CH + 16 + d];
    float x2 = sab[864 + r * CH + 16 + 64 + d];
    sab[864 + r * CH + 16 + d]      = x1 * c + x2 * s;
    sab[864 + r * CH + 16 + 64 + d] = x2 * c - x1 * s;
  }
  __syncthreads();

  const int h  = threadIdx.x >> 4;
  const int d0 = (threadIdx.x & 15) * 8;

  {
    float aq[RQ];
#pragma unroll
    for (int r = 0; r < RQ; ++r) aq[r] = sab[r * CH + h];
    union { unsigned short u16[8]; uint4 v; } pk;
#pragma unroll
    for (int j = 0; j < 8; ++j){
      float acc = 0.f;
#pragma unroll
      for (int r = 0; r < RQ; ++r) acc += aq[r] * sab[r * CH + 16 + d0 + j];
      pk.u16[j] = f2bf(acc * QSCL);
    }
    *(uint4*)&qb[((size_t)(b * 16 + h) * T_SEQ + t) * DHEAD + d0] = pk.v;
  }
  {
    float a0 = sab[864 + 0 * CH + h], a1 = sab[864 + 1 * CH + h];
    union { unsigned short u16[8]; uint4 v; } pk;
#pragma unroll
    for (int j = 0; j < 8; ++j){
      float acc = a0 * sab[864 + 0 * CH + 16 + d0 + j] + a1 * sab[864 + 1 * CH + 16 + d0 + j];
      pk.u16[j] = f2bf(acc * 0.5f);
    }
    *(uint4*)&kb[((size_t)(b * 16 + h) * T_SEQ + t) * DHEAD + d0] = pk.v;
  }
  {
    float a0 = sab[864 + 2 * CH + h], a1 = sab[864 + 3 * CH + h];
    union { unsigned short u16[8]; uint4 v; } pk;
#pragma unroll
    for (int j = 0; j < 8; ++j){
      float acc = a0 * sab[864 + 2 * CH + 16 + d0 + j] + a1 * sab[864 + 3 * CH + 16 + d0 + j];
      pk.u16[j] = f2bf(acc * 0.5f);
    }
    *(uint4*)&vb[((size_t)(b * 16 + h) * T_SEQ + t) * DHEAD + d0] = pk.v;
  }
}

// ---------------- MFMA causal flash attention (v5: swapped QK^T, lane-local softmax) ----------------
// v3 structure (256 blocks x 512 thr, 8 waves x 16 q-rows, uniform heavy+light pair,
// dbuf K/V, T14 V split-stage) + swapped S^T = mfma(K,Q):
//   S^T fragment: lane holds q = qrow0+lo (full row), kv = kt*64 + cb*16 + hi*4 + r.
//   Softmax: in-reg reduce over 16 + shfl_xor(16,32) — 2 shuffles (vs 32 DS-ops before).
//   P store: 4x ds_write_b64 to Ps[row=lo][granule (cb ^ (lo&3))] (144B row stride);
//   P read: 2x ds_read_b128 -> A-operand of PV. O/epilogue layout unchanged.
__global__ __launch_bounds__(512) void attn_mfma(const unsigned short* __restrict__ qg,
                                                 const unsigned short* __restrict__ kg,
                                                 const unsigned short* __restrict__ vg,
                                                 unsigned short* __restrict__ yg){
  __shared__ __align__(16) unsigned short Ks[2 * 64 * DHEAD];   // 32 KB
  __shared__ __align__(16) unsigned short Vt[2 * DHEAD * 64];   // 32 KB
  __shared__ __align__(16) unsigned short Ps[8 * 16 * 72];      // 18 KB (72 u16 = 144B row)

  const int bi   = blockIdx.x;
  const int xcd  = bi & 7;
  const int slot = bi >> 3;               // 0..31
  const int bh   = (slot & 3) * 8 + xcd;  // 0..31
  const int pr   = slot >> 2;             // 0..7
  const int b    = bh >> 4;
  const int h    = bh & 15;
  const size_t base = (size_t)bh * T_SEQ * DHEAD;

  const int lane = threadIdx.x & 63;
  const int wv   = threadIdx.x >> 6;      // 0..7
  const int lo   = lane & 15;
  const int hi   = lane >> 4;

  for (int phase = 0; phase < 2; ++phase){
    const int qt    = phase ? pr : (15 - pr);
    const int qrow0 = qt * 128 + wv * 16;   // 16 rows per wave

    // Q fragments (pre-scaled in qkv): Q[q=qrow0+lo][d = ds*32 + hi*8 + j]
    bf16x8 qf[4];
#pragma unroll
    for (int ds = 0; ds < 4; ++ds)
      qf[ds] = *(const bf16x8*)(qg + base + (size_t)(qrow0 + lo) * DHEAD + ds * 32 + hi * 8);

    f32x4 o4[8];
#pragma unroll
    for (int dcb = 0; dcb < 8; ++dcb) o4[dcb] = (f32x4){0.f,0.f,0.f,0.f};
    float mrow = -1e30f, lsum = 0.f;      // per-lane: q = qrow0 + lo

    const int nt = 2 * qt + 2;

    // prologue: stage tile 0 into buffer 0 (512 threads: 2 K-chunks + 2 V-chunks each)
    {
#pragma unroll
      for (int i = 0; i < 2; ++i){
        int c    = (i * 8 + wv) * 64 + lane;        // chunk id 0..1023
        int row  = c >> 4;
        int gcol = (c & 15) ^ (row & 7);
        const unsigned short* src = kg + base + (size_t)row * DHEAD + gcol * 8;
        __builtin_amdgcn_global_load_lds((const __attribute__((address_space(1))) void*)src,
                                         (__attribute__((address_space(3))) void*)&Ks[(i * 8 + wv) * 512], 16, 0, 0);
      }
      uint4 tv[2];
#pragma unroll
      for (int i = 0; i < 2; ++i)
        tv[i] = *(const uint4*)(vg + base + (size_t)lane * DHEAD + (i * 8 + wv) * 8);
#pragma unroll
      for (int i = 0; i < 2; ++i){
        int d0 = (i * 8 + wv) * 8;
        union { uint4 v; unsigned short u[8]; } t2; t2.v = tv[i];
#pragma unroll
        for (int j = 0; j < 8; ++j)
          Vt[(d0 + j) * 64 + (lane ^ (j << 3))] = t2.u[j];
      }
      __syncthreads();
    }

    for (int kt = 0; kt < nt; ++kt){
      const int cur = kt & 1;
      const int nxt = cur ^ 1;
      const bool pf = (kt + 1 < nt);
      uint4 tv[2];
      if (pf){
        // prefetch K(kt+1) straight to LDS buffer nxt
#pragma unroll
        for (int i = 0; i < 2; ++i){
          int c    = (i * 8 + wv) * 64 + lane;
          int row  = c >> 4;
          int gcol = (c & 15) ^ (row & 7);
          const unsigned short* src = kg + base + (size_t)((kt + 1) * 64 + row) * DHEAD + gcol * 8;
          __builtin_amdgcn_global_load_lds((const __attribute__((address_space(1))) void*)src,
                                           (__attribute__((address_space(3))) void*)&Ks[nxt * 8192 + (i * 8 + wv) * 512], 16, 0, 0);
        }
        // prefetch V(kt+1) to registers
#pragma unroll
        for (int i = 0; i < 2; ++i)
          tv[i] = *(const uint4*)(vg + base + (size_t)((kt + 1) * 64 + lane) * DHEAD + (i * 8 + wv) * 8);
      }

      if (kt * 64 <= qrow0 + 15){   // wave has unmasked work in this tile
        const unsigned short* Kb = &Ks[cur * 8192];
        const unsigned short* Vb = &Vt[cur * 8192];

        // ---- S^T = K Q^T : s4[cb][r] = S[q=qrow0+lo][kv = kt*64 + cb*16 + hi*4 + r] ----
        f32x4 s4[4];
#pragma unroll
        for (int cb = 0; cb < 4; ++cb) s4[cb] = (f32x4){0.f,0.f,0.f,0.f};
        __builtin_amdgcn_s_setprio(1);
#pragma unroll
        for (int ds = 0; ds < 4; ++ds){
          bf16x8 kf[4];
#pragma unroll
          for (int cb = 0; cb < 4; ++cb){
            int kvr = cb * 16 + lo;
            kf[cb] = *(const bf16x8*)&Kb[kvr * DHEAD + ((ds * 32 + hi * 8) ^ ((kvr & 7) << 3))];
          }
#pragma unroll
          for (int cb = 0; cb < 4; ++cb)
            s4[cb] = __builtin_amdgcn_mfma_f32_16x16x32_bf16(kf[cb], qf[ds], s4[cb], 0, 0, 0);
        }
        __builtin_amdgcn_s_setprio(0);

        // ---- causal mask (diagonal tiles only) ----
        const int qrow = qrow0 + lo;
        if (kt * 64 + 63 > qrow0){
#pragma unroll
          for (int cb = 0; cb < 4; ++cb)
#pragma unroll
            for (int r = 0; r < 4; ++r){
              int kv = kt * 64 + cb * 16 + hi * 4 + r;
              if (kv > qrow) s4[cb][r] = -1e30f;
            }
        }

        // ---- online softmax (exp2 domain), lane-local row, defer-max ----
        float mx = s4[0][0];
#pragma unroll
        for (int cb = 0; cb < 4; ++cb)
#pragma unroll
          for (int r = 0; r < 4; ++r) mx = fmaxf(mx, s4[cb][r]);
        mx = fmaxf(mx, __shfl_xor(mx, 16));
        mx = fmaxf(mx, __shfl_xor(mx, 32));

        if (__any(mx > mrow + 8.f)){
          float mN = fmaxf(mrow, mx);
          float alpha = EXP2(mrow - mN);
          mrow = mN;
          lsum *= alpha;
          // o4 rows are q = hi*4+r: fetch that row's alpha (lanes 0..15 hold q=lo)
#pragma unroll
          for (int r = 0; r < 4; ++r){
            float ar = __shfl(alpha, hi * 4 + r);
#pragma unroll
            for (int dcb = 0; dcb < 8; ++dcb) o4[dcb][r] *= ar;
          }
        }

        float p[4][4];
        float psum = 0.f;
#pragma unroll
        for (int cb = 0; cb < 4; ++cb)
#pragma unroll
          for (int r = 0; r < 4; ++r){
            float v = EXP2(s4[cb][r] - mrow);
            p[cb][r] = v;
            psum += v;
          }
        psum += __shfl_xor(psum, 16);
        psum += __shfl_xor(psum, 32);
        lsum += psum;

        // ---- P store: row = wv*16+lo (144B stride), granule cb ^ (lo&3), sub hi*8B ----
#pragma unroll
        for (int cb = 0; cb < 4; ++cb){
          unsigned u0 = (unsigned)f2bf(p[cb][0]) | ((unsigned)f2bf(p[cb][1]) << 16);
          unsigned u1 = (unsigned)f2bf(p[cb][2]) | ((unsigned)f2bf(p[cb][3]) << 16);
          uint2 w; w.x = u0; w.y = u1;
          int off = (wv * 16 + lo) * 72 + ((cb ^ (lo & 3)) * 16) + hi * 4;   // u16 units
          *(uint2*)&Ps[off] = w;
        }

        // wave-local P round-trip: ensure ds_writes retired before ds_reads
        asm volatile("s_waitcnt lgkmcnt(0)" ::: "memory");

        // ---- O += P V : A = P[q=lo][kv=ks*32+hi*8+j], B = V^T ----
        __builtin_amdgcn_s_setprio(1);
#pragma unroll
        for (int ks = 0; ks < 2; ++ks){
          bf16x8 pa;
          {
            int g = (2 * ks + (hi >> 1)) ^ (lo & 3);
            int off = (wv * 16 + lo) * 72 + g * 16 + (hi & 1) * 8;           // u16 units
            pa = *(const bf16x8*)&Ps[off];
          }
#pragma unroll
          for (int dcb = 0; dcb < 8; ++dcb){
            int d = dcb * 16 + lo;
            bf16x8 vf = *(const bf16x8*)&Vb[d * 64 + ((ks * 32 + hi * 8) ^ ((d & 7) << 3))];
            o4[dcb] = __builtin_amdgcn_mfma_f32_16x16x32_bf16(pa, vf, o4[dcb], 0, 0, 0);
          }
        }
        __builtin_amdgcn_s_setprio(0);
      }

      if (pf){
        // write prefetched V into buffer nxt (compiler waits vmcnt for tv here)
#pragma unroll
        for (int i = 0; i < 2; ++i){
          int d0 = (i * 8 + wv) * 8;
          union { uint4 v; unsigned short u[8]; } t2; t2.v = tv[i];
#pragma unroll
          for (int j = 0; j < 8; ++j)
            Vt[nxt * 8192 + (d0 + j) * 64 + (lane ^ (j << 3))] = t2.u[j];
        }
      }
      __syncthreads();   // drains K global_load_lds for kt+1; fences buffers
    }

    // ---- epilogue: normalize + store bf16 y[b, t, h*128 + d] ----
#pragma unroll
    for (int r = 0; r < 4; ++r){
      float lr  = __shfl(lsum, hi * 4 + r);
      float inv = 1.f / lr;
      int q = qrow0 + hi * 4 + r;
      size_t yb_ = ((size_t)(b * T_SEQ + q)) * DMODEL + h * DHEAD;
#pragma unroll
      for (int dcb = 0; dcb < 8; ++dcb)
        yg[yb_ + dcb * 16 + lo] = f2bf(o4[dcb][r] * inv);
    }
    __syncthreads();   // phase barrier before buffers are restaged
  }
}

// ---------------- launch ----------------
extern "C" void kernel_launch(void* const* d_in, const int* in_sizes, int n_in,
                              void* d_out, int out_size, void* d_ws, size_t ws_size,
                              hipStream_t stream) {
  const float* x   = (const float*)d_in[0];
  const float* Wq  = (const float*)d_in[1];
  const float* Wkv = (const float*)d_in[2];
  const float* Wo  = (const float*)d_in[3];
  float* out = (float*)d_out;

  char* ws = (char*)d_ws;
  size_t off = 0;
  auto alloc = [&](size_t bytes) -> void* {
    void* p = ws + off;
    off += (bytes + 255) & ~(size_t)255;
    return p;
  };
  unsigned short* xb = (unsigned short*)alloc((size_t)MROWS * DMODEL * 2);
  unsigned short* wc = (unsigned short*)alloc((size_t)N1P * DMODEL * 2);
  unsigned short* wo = (unsigned short*)alloc((size_t)DMODEL * DMODEL * 2);
  float*          abf = (float*)alloc((size_t)MROWS * N1P * 4);
  unsigned short* qb = (unsigned short*)alloc((size_t)MROWS * DMODEL * 2);
  unsigned short* kb = (unsigned short*)alloc((size_t)MROWS * DMODEL * 2);
  unsigned short* vb = (unsigned short*)alloc((size_t)MROWS * DMODEL * 2);
  unsigned short* yb = (unsigned short*)alloc((size_t)MROWS * DMODEL * 2);

  {
    int n4 = MROWS * DMODEL / 4;
    cast_f32_bf16<<<2048, 256, 0, stream>>>(x, xb, n4);
    n4 = RQ * CH * DMODEL / 4;
    cast_f32_bf16<<<1024, 256, 0, stream>>>(Wq, wc, n4);
    n4 = RKV * CH * DMODEL / 4;
    cast_f32_bf16<<<1024, 256, 0, stream>>>(Wkv, wc + (size_t)RQ * CH * DMODEL, n4);
    int npad = (N1P - N1) * DMODEL;
    zero_u16<<<(npad + 255) / 256, 256, 0, stream>>>(wc + (size_t)N1 * DMODEL, npad);
    n4 = DMODEL * DMODEL / 4;
    cast_f32_bf16<<<2048, 256, 0, stream>>>(Wo, wo, n4);
  }

  gemm_bt<<<dim3(N1P / 128, MROWS / 128), 256, 0, stream>>>(xb, wc, abf, MROWS, N1P, DMODEL);
  qkv_kernel<<<MROWS, 256, 0, stream>>>(abf, qb, kb, vb);
  attn_mfma<<<256, 512, 0, stream>>>(qb, kb, vb, yb);
  gemm_bt<<<dim3(DMODEL / 128, MROWS / 128), 256, 0, stream>>>(yb, wo, out, MROWS, DMODEL, DMODEL);
}